// Round 2
// baseline (4126.735 us; speedup 1.0000x reference)
//
#include <hip/hip_runtime.h>
#include <hip/hip_fp16.h>

// TanhFixedPointLayer: z_{k+1} = tanh(z_k @ W^T + x), z0 = 0, 50 iterations.
// Round-2 restructure: OCCUPANCY. Previous kernels sat at 192 unified regs
// (128 VGPR + 64 AGPR) -> 2 waves/SIMD; every stall idled the SIMD and no
// prefetch/barrier change moved the needle. This version targets the
// <=128-reg band -> 4 waves/SIMD (16 waves/CU):
//  - 1024-thread blocks (16 waves), MTILE=64 unchanged -> W L2 traffic
//    unchanged (wave owns 2 n-frags; no A duplication across waves).
//  - per-wave tile 32n x 64m: acc = 2x4 frags = 32 AGPR (was 64).
//  - x NOT kept in registers: re-loaded (nontemporal) from global each
//    epilogue, 16 transient regs at a time. Costs ~6.4 GB streamed reads
//    over the kernel (~25% more FETCH), buys 64 registers.
//  - A-frag prefetch depth-2 with modular index (wraps across iterations);
//    barrier done in inline asm (lgkmcnt(0); s_barrier) so the compiler's
//    vmcnt(0) pre-barrier drain doesn't kill the cross-iteration prefetch.
//  - B-frags (z from LDS) double-buffered, depth-2.

#define DDIM  512
#define MTILE 64
#define NITER 50     // z1 = tanh(x) counts as iteration 1; 49 MFMA iterations

typedef _Float16 half8  __attribute__((ext_vector_type(8)));
typedef _Float16 half4v __attribute__((ext_vector_type(4)));
typedef float    float4v __attribute__((ext_vector_type(4)));

__device__ __forceinline__ float fast_tanh(float t) {
    // tanh(t) = 1 - 2/(exp(2t)+1); exp(2t) = 2^(t*2*log2(e)); exact +-1 at sat.
    float e = __builtin_amdgcn_exp2f(t * 2.8853900817779268f);
    return 1.0f - 2.0f * __builtin_amdgcn_rcpf(e + 1.0f);
}

// z LDS layout = frag-packed: element (m,k) at
//   ((k>>5)*4 + (m>>4))*512 + ((m&15) + 16*((k>>3)&3))*8 + (k&7)
// so B-frag (mf,ks) for lane L is the 16B chunk at ((ks*4+mf)*64 + L)*8.
__device__ __forceinline__ int zaddr(int m, int k) {
    return (((k >> 5) * 4 + (m >> 4)) << 9) + (((m & 15) + (((k >> 3) & 3) << 4)) << 3) + (k & 7);
}

// ---- prep: pack W (fp32 [512][512]) into f16 MFMA A-frag order.
// Frag (ks, nf) block = 64 lanes x 16B: lane L holds
//   W[nf*16 + (L&15)][ks*32 + (L>>4)*8 + j], j=0..7
__global__ void wpack_kernel(const float* __restrict__ W, _Float16* __restrict__ Wpk) {
    int gid  = blockIdx.x * blockDim.x + threadIdx.x;   // 0..32767
    int ks   = gid >> 11;
    int nf   = (gid >> 6) & 31;
    int lane = gid & 63;
    int row  = nf * 16 + (lane & 15);
    int col  = ks * 32 + (lane >> 4) * 8;
    const float* src = W + row * DDIM + col;
    half8 h;
#pragma unroll
    for (int j = 0; j < 8; ++j) h[j] = (_Float16)src[j];
    *(half8*)(Wpk + (size_t)gid * 8) = h;
}

__global__ __launch_bounds__(1024, 4)
void fixpoint_kernel(const float* __restrict__ x,
                     const _Float16* __restrict__ Wpk,
                     float* __restrict__ out) {
    __shared__ __align__(16) _Float16 zsh[2][MTILE * DDIM];   // 2 x 64 KB

    const int tid  = threadIdx.x;
    const int lane = tid & 63;
    const int wid  = tid >> 6;          // 0..15, each wave owns 32 n-columns
    const int l15  = lane & 15;
    const int quad = lane >> 4;
    const int nf0  = wid * 2;           // first of this wave's 2 n-frags

    const int row_blk = blockIdx.x * MTILE;
    // A-frag (ks, nf0+f) for this lane: Wv[(ks*32 + f)*64]
    const half8* Wv = (const half8*)Wpk + nf0 * 64 + lane;

    // ---- z1 = tanh(x) -> zsh[0] (x loaded nontemporal, transient regs only)
#pragma unroll
    for (int f = 0; f < 2; ++f) {
        int n = (nf0 + f) * 16 + quad * 4;
#pragma unroll
        for (int mf = 0; mf < 4; ++mf) {
            const float4v* xp = (const float4v*)(x + (size_t)(row_blk + mf * 16 + l15) * DDIM + n);
            float4v xv = __builtin_nontemporal_load(xp);
            half4v h;
#pragma unroll
            for (int j = 0; j < 4; ++j) h[j] = (_Float16)fast_tanh(xv[j]);
            *(half4v*)(&zsh[0][zaddr(mf * 16 + l15, n)]) = h;
        }
    }
    __syncthreads();

    // ---- A prefetch for ks=0,1 (z-independent, survives barriers)
    half8 X0[2], X1[2];
#pragma unroll
    for (int f = 0; f < 2; ++f) X0[f] = Wv[f * 64];
#pragma unroll
    for (int f = 0; f < 2; ++f) X1[f] = Wv[(32 + f) * 64];

    int p = 0;
    for (int it = 0; it < NITER - 1; ++it) {
        const _Float16* zr = &zsh[p][0];

        // B-frag double buffer (depth 2)
        half8 B0[4], B1[4];
#pragma unroll
        for (int mf = 0; mf < 4; ++mf) B0[mf] = *(const half8*)(zr + (mf * 64 + lane) * 8);
#pragma unroll
        for (int mf = 0; mf < 4; ++mf) B1[mf] = *(const half8*)(zr + ((4 + mf) * 64 + lane) * 8);

        float4v acc[2][4];
#pragma unroll
        for (int f = 0; f < 2; ++f)
#pragma unroll
            for (int mf = 0; mf < 4; ++mf) acc[f][mf] = (float4v){0.f, 0.f, 0.f, 0.f};

#pragma unroll
        for (int ks = 0; ks < 16; ++ks) {
            half8* Ac = (ks & 1) ? X1 : X0;
            half8* Bc = (ks & 1) ? B1 : B0;
#pragma unroll
            for (int f = 0; f < 2; ++f)
#pragma unroll
                for (int mf = 0; mf < 4; ++mf)
                    acc[f][mf] = __builtin_amdgcn_mfma_f32_16x16x32_f16(Ac[f], Bc[mf], acc[f][mf], 0, 0, 0);
            // Refill just-consumed A buffer with ks+2 (mod 16): at ks=14,15
            // this prefetches the NEXT iteration's ks=0,1 across the barrier
            // (asm barrier below does not drain vmcnt).
            {
                int ka = (ks + 2) & 15;
#pragma unroll
                for (int f = 0; f < 2; ++f) Ac[f] = Wv[(ka * 32 + f) * 64];
            }
            // Refill B with ks+2 from the SAME z buffer (cannot cross barrier).
            if (ks < 14) {
#pragma unroll
                for (int mf = 0; mf < 4; ++mf)
                    Bc[mf] = *(const half8*)(zr + (((ks + 2) * 4 + mf) * 64 + lane) * 8);
            }
        }

        if (it < NITER - 2) {
            // z_{k+1} = tanh(acc + x) -> other buffer; x re-loaded (nt),
            // processed one f-group at a time to cap transient registers.
            _Float16* zw = &zsh[p ^ 1][0];
#pragma unroll
            for (int f = 0; f < 2; ++f) {
                int n = (nf0 + f) * 16 + quad * 4;
                float4v xv[4];
#pragma unroll
                for (int mf = 0; mf < 4; ++mf) {
                    const float4v* xp = (const float4v*)(x + (size_t)(row_blk + mf * 16 + l15) * DDIM + n);
                    xv[mf] = __builtin_nontemporal_load(xp);
                }
#pragma unroll
                for (int mf = 0; mf < 4; ++mf) {
                    half4v h;
#pragma unroll
                    for (int j = 0; j < 4; ++j) h[j] = (_Float16)fast_tanh(acc[f][mf][j] + xv[mf][j]);
                    *(half4v*)(zw + zaddr(mf * 16 + l15, n)) = h;
                }
            }
            // Barrier WITHOUT vmcnt drain: LDS writes must be visible
            // (lgkmcnt(0)), but in-flight global A-prefetch loads stay live.
            asm volatile("s_waitcnt lgkmcnt(0)\n\ts_barrier" ::: "memory");
            p ^= 1;
        } else {
            // final iteration: store z50 straight from registers (fp32, nt)
#pragma unroll
            for (int f = 0; f < 2; ++f) {
                int n = (nf0 + f) * 16 + quad * 4;
#pragma unroll
                for (int mf = 0; mf < 4; ++mf) {
                    const float4v* xp = (const float4v*)(x + (size_t)(row_blk + mf * 16 + l15) * DDIM + n);
                    float4v xv = __builtin_nontemporal_load(xp);
                    float4v v;
#pragma unroll
                    for (int j = 0; j < 4; ++j) v[j] = fast_tanh(acc[f][mf][j] + xv[j]);
                    float4v* op = (float4v*)(out + (size_t)(row_blk + mf * 16 + l15) * DDIM + n);
                    __builtin_nontemporal_store(v, op);
                }
            }
        }
    }
}

extern "C" void kernel_launch(void* const* d_in, const int* in_sizes, int n_in,
                              void* d_out, int out_size, void* d_ws, size_t ws_size,
                              hipStream_t stream) {
    const float* x = (const float*)d_in[0];   // [65536, 512] fp32
    const float* W = (const float*)d_in[1];   // [512, 512] fp32
    _Float16* Wpk = (_Float16*)d_ws;          // 512 KB packed f16 W
    float* out = (float*)d_out;

    wpack_kernel<<<128, 256, 0, stream>>>(W, Wpk);
    fixpoint_kernel<<<65536 / MTILE, 1024, 0, stream>>>(x, Wpk, out);
}

// Round 3
// 3483.698 us; speedup vs baseline: 1.1846x; 1.1846x over previous
//
#include <hip/hip_runtime.h>
#include <hip/hip_fp16.h>

// TanhFixedPointLayer: z_{k+1} = tanh(z_k @ W^T + x), z0 = 0, 50 iterations.
// Round-3: XCD PHASE-LOCK. Empirical law from R0-R2: dur tracks L2-miss bytes
// at ~4-5 B/cyc/CU; W (512 KB, should be L2-resident) misses at a constant
// ~32% because 32 CUs/XCD stream it circularly at drifting phase offsets.
// Fix: per-XCD cohort barrier each iteration (arrival ticket keyed by the HW
// XCC_ID register) so all 32 co-resident blocks sweep W in-phase within ~1us
// -> first toucher misses, 31 hit/merge. Lock is a pure scheduling hint (W is
// immutable: no fences needed); spin is bounded and self-disabling, so the
// worst case is baseline + ~50us.
// Compute structure = proven R0/R1 shape: 512 thr (8 waves, 2/SIMD), x held
// in registers (acc init = x), depth-2 A prefetch wrapping across iterations,
// z double-buffered in LDS, single lgkm-only asm barrier per iteration (no
// vmcnt drain -> cross-iteration W prefetch stays in flight). nt hints only
// on the final out stores.

#define DDIM  512
#define MTILE 64
#define NITER 50      // z1 = tanh(x) counts as iteration 1; 49 MFMA iterations

#define XCDS        8
#define CUS_PER_XCD 32
#define COH_MAX     8     // cohorts per XCD (1024 blocks / 8 XCD / 32 = 4 used)
#define ITER_SLOTS  64    // padded slots for 49 locks
#define MAXSPIN     400   // ~50us cap; one timeout disables locking for block

typedef _Float16 half8  __attribute__((ext_vector_type(8)));
typedef _Float16 half4v __attribute__((ext_vector_type(4)));
typedef float    float4v __attribute__((ext_vector_type(4)));

__device__ __forceinline__ float fast_tanh(float t) {
    // tanh(t) = 1 - 2/(exp(2t)+1); exp(2t) = 2^(t*2*log2(e)); exact +-1 at sat.
    float e = __builtin_amdgcn_exp2f(t * 2.8853900817779268f);
    return 1.0f - 2.0f * __builtin_amdgcn_rcpf(e + 1.0f);
}

// z LDS layout = frag-packed: element (m,k) at
//   ((k>>5)*4 + (m>>4))*512 + ((m&15) + 16*((k>>3)&3))*8 + (k&7)
// so B-frag (mf,ks) for lane L is the 16B chunk at ((ks*4+mf)*64 + L)*8.
__device__ __forceinline__ int zaddr(int m, int k) {
    return (((k >> 5) * 4 + (m >> 4)) << 9) + (((m & 15) + (((k >> 3) & 3) << 4)) << 3) + (k & 7);
}

// Per-XCD cohort barrier: add-then-spin until all 32 co-resident blocks of
// this XCD arrive. Perf-only (no data ordering depends on it). Bounded spin;
// on timeout the block permanently stops locking (damage <= one MAXSPIN).
__device__ __forceinline__ void xcd_phase_lock(unsigned* c, bool& on) {
    if (!on) return;
    __hip_atomic_fetch_add(c, 1u, __ATOMIC_RELAXED, __HIP_MEMORY_SCOPE_AGENT);
    int s = 0;
    while (__hip_atomic_load(c, __ATOMIC_RELAXED, __HIP_MEMORY_SCOPE_AGENT) < CUS_PER_XCD) {
        if (++s >= MAXSPIN) { on = false; return; }
        __builtin_amdgcn_s_sleep(2);
    }
}

__global__ void zinit_kernel(unsigned* __restrict__ ctr) {
    int i = blockIdx.x * blockDim.x + threadIdx.x;
    if (i < XCDS + XCDS * COH_MAX * ITER_SLOTS) ctr[i] = 0u;
}

// ---- prep: pack W (fp32 [512][512]) into f16 MFMA A-frag order.
// Frag (ks, nf) block = 64 lanes x 16B: lane L holds
//   W[nf*16 + (L&15)][ks*32 + (L>>4)*8 + j], j=0..7
__global__ void wpack_kernel(const float* __restrict__ W, _Float16* __restrict__ Wpk) {
    int gid  = blockIdx.x * blockDim.x + threadIdx.x;   // 0..32767
    int ks   = gid >> 11;
    int nf   = (gid >> 6) & 31;
    int lane = gid & 63;
    int row  = nf * 16 + (lane & 15);
    int col  = ks * 32 + (lane >> 4) * 8;
    const float* src = W + row * DDIM + col;
    half8 h;
#pragma unroll
    for (int j = 0; j < 8; ++j) h[j] = (_Float16)src[j];
    *(half8*)(Wpk + (size_t)gid * 8) = h;
}

__global__ __launch_bounds__(512, 2)
void fixpoint_kernel(const float* __restrict__ x,
                     const _Float16* __restrict__ Wpk,
                     float* __restrict__ out,
                     unsigned* __restrict__ ctr) {
    __shared__ __align__(16) _Float16 zsh[2][MTILE * DDIM];   // 2 x 64 KB

    const int tid  = threadIdx.x;
    const int lane = tid & 63;
    const int wid  = tid >> 6;          // 0..7, each wave owns 64 n-columns
    const int l15  = lane & 15;
    const int quad = lane >> 4;
    const int nf0  = wid * 4;           // first of this wave's 4 n-frags

    const int row_blk = blockIdx.x * MTILE;
    // A-frag (ks, nf0+f) for this lane: Wv[(ks*32 + f)*64]
    const half8* Wv = (const half8*)Wpk + nf0 * 64 + lane;

    // ---- cohort identity from the HARDWARE XCC id + arrival ticket.
    bool lock_on = true;
    unsigned lockbase = 0;
    if (tid == 0) {
        unsigned xcd;
        asm volatile("s_getreg_b32 %0, hwreg(HW_REG_XCC_ID)" : "=s"(xcd));
        xcd &= (XCDS - 1);
        unsigned t = __hip_atomic_fetch_add(ctr + xcd, 1u, __ATOMIC_RELAXED,
                                            __HIP_MEMORY_SCOPE_AGENT);
        lockbase = XCDS + (xcd * COH_MAX + ((t >> 5) & (COH_MAX - 1))) * ITER_SLOTS;
    }

    // ---- x in registers at this lane's C/D slots:
    // xr[f][mf][r] = x[mf*16+l15][(nf0+f)*16 + quad*4 + r]
    float4v xr[4][4];
#pragma unroll
    for (int f = 0; f < 4; ++f) {
        int n = (nf0 + f) * 16 + quad * 4;
#pragma unroll
        for (int mf = 0; mf < 4; ++mf) {
            xr[f][mf] = *(const float4v*)(x + (size_t)(row_blk + mf * 16 + l15) * DDIM + n);
        }
    }

    // ---- A prefetch for ks=0,1 (z-independent, survives lgkm-only barriers)
    half8 A0[4], A1[4];
#pragma unroll
    for (int f = 0; f < 4; ++f) A0[f] = Wv[f * 64];
#pragma unroll
    for (int f = 0; f < 4; ++f) A1[f] = Wv[(32 + f) * 64];

    // ---- z1 = tanh(x) -> zsh[0] (b64 contiguous writes)
#pragma unroll
    for (int f = 0; f < 4; ++f) {
        int n = (nf0 + f) * 16 + quad * 4;
#pragma unroll
        for (int mf = 0; mf < 4; ++mf) {
            int m = mf * 16 + l15;
            half4v h;
#pragma unroll
            for (int j = 0; j < 4; ++j) h[j] = (_Float16)fast_tanh(xr[f][mf][j]);
            *(half4v*)(&zsh[0][zaddr(m, n)]) = h;
        }
    }
    if (tid == 0) xcd_phase_lock(ctr + lockbase + 0, lock_on);
    asm volatile("s_waitcnt lgkmcnt(0)\n\ts_barrier" ::: "memory");

    int p = 0;
    for (int it = 0; it < NITER - 1; ++it) {
        const _Float16* zr = &zsh[p][0];

        // B-frag double buffer (depth 2)
        half8 B0[4], B1[4];
#pragma unroll
        for (int mf = 0; mf < 4; ++mf) B0[mf] = *(const half8*)(zr + (mf * 64 + lane) * 8);
#pragma unroll
        for (int mf = 0; mf < 4; ++mf) B1[mf] = *(const half8*)(zr + ((4 + mf) * 64 + lane) * 8);

        // acc starts at x: MFMA C-in accumulates, epilogue add eliminated
        float4v acc[4][4];
#pragma unroll
        for (int f = 0; f < 4; ++f)
#pragma unroll
            for (int mf = 0; mf < 4; ++mf) acc[f][mf] = xr[f][mf];

#pragma unroll
        for (int ks = 0; ks < 16; ++ks) {
            half8* Ac = (ks & 1) ? A1 : A0;
            half8* Bc = (ks & 1) ? B1 : B0;
#pragma unroll
            for (int f = 0; f < 4; ++f)
#pragma unroll
                for (int mf = 0; mf < 4; ++mf)
                    acc[f][mf] = __builtin_amdgcn_mfma_f32_16x16x32_f16(Ac[f], Bc[mf], acc[f][mf], 0, 0, 0);
            // Refill just-consumed A buffer with ks+2 (mod 16): at ks=14,15
            // this prefetches the NEXT iteration's ks=0,1 across the barrier.
            {
                int ka = (ks + 2) & 15;
#pragma unroll
                for (int f = 0; f < 4; ++f) Ac[f] = Wv[(ka * 32 + f) * 64];
            }
            // Refill B with ks+2 from the SAME z buffer (cannot cross barrier).
            if (ks < 14) {
#pragma unroll
                for (int mf = 0; mf < 4; ++mf)
                    Bc[mf] = *(const half8*)(zr + (((ks + 2) * 4 + mf) * 64 + lane) * 8);
            }
        }

        if (it < NITER - 2) {
            // z_{k+1} = tanh(acc) -> other buffer (readers on zsh[p], writers
            // on zsh[p^1]: one barrier per iteration is sufficient).
            _Float16* zw = &zsh[p ^ 1][0];
#pragma unroll
            for (int f = 0; f < 4; ++f) {
                int n = (nf0 + f) * 16 + quad * 4;
#pragma unroll
                for (int mf = 0; mf < 4; ++mf) {
                    int m = mf * 16 + l15;
                    half4v h;
#pragma unroll
                    for (int j = 0; j < 4; ++j) h[j] = (_Float16)fast_tanh(acc[f][mf][j]);
                    *(half4v*)(zw + zaddr(m, n)) = h;
                }
            }
            // Keep the XCD cohort in phase for the next W sweep, then barrier
            // WITHOUT vmcnt drain (A-prefetch loads stay in flight).
            if (tid == 0) xcd_phase_lock(ctr + lockbase + (it + 1), lock_on);
            asm volatile("s_waitcnt lgkmcnt(0)\n\ts_barrier" ::: "memory");
            p ^= 1;
        } else {
            // final iteration: store z50 straight from registers (fp32, nt)
#pragma unroll
            for (int f = 0; f < 4; ++f) {
                int n = (nf0 + f) * 16 + quad * 4;
#pragma unroll
                for (int mf = 0; mf < 4; ++mf) {
                    float4v v;
#pragma unroll
                    for (int j = 0; j < 4; ++j) v[j] = fast_tanh(acc[f][mf][j]);
                    float4v* op = (float4v*)(out + (size_t)(row_blk + mf * 16 + l15) * DDIM + n);
                    __builtin_nontemporal_store(v, op);
                }
            }
        }
    }
}

extern "C" void kernel_launch(void* const* d_in, const int* in_sizes, int n_in,
                              void* d_out, int out_size, void* d_ws, size_t ws_size,
                              hipStream_t stream) {
    const float* x = (const float*)d_in[0];   // [65536, 512] fp32
    const float* W = (const float*)d_in[1];   // [512, 512] fp32
    _Float16* Wpk = (_Float16*)d_ws;          // 512 KB packed f16 W
    unsigned* ctr = (unsigned*)((char*)d_ws + 512 * 1024);  // lock counters
    float* out = (float*)d_out;

    zinit_kernel<<<17, 256, 0, stream>>>(ctr);
    wpack_kernel<<<128, 256, 0, stream>>>(W, Wpk);
    fixpoint_kernel<<<65536 / MTILE, 512, 0, stream>>>(x, Wpk, out, ctr);
}

// Round 4
// 3248.608 us; speedup vs baseline: 1.2703x; 1.0724x over previous
//
#include <hip/hip_runtime.h>
#include <hip/hip_fp16.h>

// TanhFixedPointLayer: z_{k+1} = tanh(z_k @ W^T + x), z0 = 0, 50 iterations.
// Round-4: PHASE-SPREAD K-SWEEP. Three-round model: cyc/block-iter =
// ~33e3 + 80*missKB -> wall is serialized W L2-miss latency. Cause theory:
// shared misses CONVOY the 32 CUs/XCD into one pack; pack period ~18.7us; a
// W line sits untouched a full period while the pack's own refills
// (5.3 MB/period > 4 MB L2) evict it -> self-sustaining thrash.
// Fix: each block sweeps K starting at a static per-block phase,
// ks_actual = (phase+ks)&15. Co-resident blocks cover all 16 phases x2 by
// construction -> every W line touched every ~1.2us -> refill pressure
// collapses -> W becomes L2-resident. No locks, no atomics, no failure mode
// (only FP summation order changes). Phase formula covers all 16 phases
// evenly under BOTH round-robin and chunked block->XCD assignment.
// Compute structure = proven R0/R3 shape: 512 thr (8 waves, 2/SIMD), x held
// in registers (acc init = x via MFMA C-in), depth-2 A prefetch wrapping
// across iterations, z double-buffered in LDS, single lgkm-only asm barrier
// per iteration (W prefetch loads stay in flight across it).

#define DDIM  512
#define MTILE 64
#define NITER 50      // z1 = tanh(x) counts as iteration 1; 49 MFMA iterations

typedef _Float16 half8  __attribute__((ext_vector_type(8)));
typedef _Float16 half4v __attribute__((ext_vector_type(4)));
typedef float    float4v __attribute__((ext_vector_type(4)));

__device__ __forceinline__ float fast_tanh(float t) {
    // tanh(t) = 1 - 2/(exp(2t)+1); exp(2t) = 2^(t*2*log2(e)); exact +-1 at sat.
    float e = __builtin_amdgcn_exp2f(t * 2.8853900817779268f);
    return 1.0f - 2.0f * __builtin_amdgcn_rcpf(e + 1.0f);
}

// z LDS layout = frag-packed: element (m,k) at
//   ((k>>5)*4 + (m>>4))*512 + ((m&15) + 16*((k>>3)&3))*8 + (k&7)
// so B-frag (mf,ks) for lane L is the 16B chunk at ((ks*4+mf)*64 + L)*8.
__device__ __forceinline__ int zaddr(int m, int k) {
    return (((k >> 5) * 4 + (m >> 4)) << 9) + (((m & 15) + (((k >> 3) & 3) << 4)) << 3) + (k & 7);
}

// ---- prep: pack W (fp32 [512][512]) into f16 MFMA A-frag order.
// Frag (ks, nf) block = 64 lanes x 16B: lane L holds
//   W[nf*16 + (L&15)][ks*32 + (L>>4)*8 + j], j=0..7
__global__ void wpack_kernel(const float* __restrict__ W, _Float16* __restrict__ Wpk) {
    int gid  = blockIdx.x * blockDim.x + threadIdx.x;   // 0..32767
    int ks   = gid >> 11;
    int nf   = (gid >> 6) & 31;
    int lane = gid & 63;
    int row  = nf * 16 + (lane & 15);
    int col  = ks * 32 + (lane >> 4) * 8;
    const float* src = W + row * DDIM + col;
    half8 h;
#pragma unroll
    for (int j = 0; j < 8; ++j) h[j] = (_Float16)src[j];
    *(half8*)(Wpk + (size_t)gid * 8) = h;
}

__global__ __launch_bounds__(512, 2)
void fixpoint_kernel(const float* __restrict__ x,
                     const _Float16* __restrict__ Wpk,
                     float* __restrict__ out) {
    __shared__ __align__(16) _Float16 zsh[2][MTILE * DDIM];   // 2 x 64 KB

    const int tid  = threadIdx.x;
    const int lane = tid & 63;
    const int wid  = tid >> 6;          // 0..7, each wave owns 64 n-columns
    const int l15  = lane & 15;
    const int quad = lane >> 4;
    const int nf0  = wid * 4;           // first of this wave's 4 n-frags

    const int row_blk = blockIdx.x * MTILE;
    // Per-block k-sweep phase: covers all 16 phases x2 among any 32
    // co-resident blocks under round-robin OR chunked XCD assignment.
    const int phase = ((blockIdx.x >> 3) ^ ((blockIdx.x & 7) << 1)) & 15;

    // A-frag (ks, nf0+f) for this lane: Wv[(ks*32 + f)*64]
    const half8* Wv = (const half8*)Wpk + nf0 * 64 + lane;

    // ---- A prefetch for sweep steps 0,1 (k-chunks phase, phase+1)
    half8 A0[4], A1[4];
    {
        int k0 = phase, k1 = (phase + 1) & 15;
#pragma unroll
        for (int f = 0; f < 4; ++f) A0[f] = Wv[(k0 * 32 + f) * 64];
#pragma unroll
        for (int f = 0; f < 4; ++f) A1[f] = Wv[(k1 * 32 + f) * 64];
    }

    // ---- x in registers at this lane's C/D slots:
    // xr[f][mf][r] = x[mf*16+l15][(nf0+f)*16 + quad*4 + r]
    float4v xr[4][4];
#pragma unroll
    for (int f = 0; f < 4; ++f) {
        int n = (nf0 + f) * 16 + quad * 4;
#pragma unroll
        for (int mf = 0; mf < 4; ++mf) {
            xr[f][mf] = *(const float4v*)(x + (size_t)(row_blk + mf * 16 + l15) * DDIM + n);
        }
    }

    // ---- z1 = tanh(x) -> zsh[0] (b64 contiguous writes)
#pragma unroll
    for (int f = 0; f < 4; ++f) {
        int n = (nf0 + f) * 16 + quad * 4;
#pragma unroll
        for (int mf = 0; mf < 4; ++mf) {
            int m = mf * 16 + l15;
            half4v h;
#pragma unroll
            for (int j = 0; j < 4; ++j) h[j] = (_Float16)fast_tanh(xr[f][mf][j]);
            *(half4v*)(&zsh[0][zaddr(m, n)]) = h;
        }
    }
    asm volatile("s_waitcnt lgkmcnt(0)\n\ts_barrier" ::: "memory");

    int p = 0;
    for (int it = 0; it < NITER - 1; ++it) {
        const _Float16* zr = &zsh[p][0];

        // B-frag double buffer (depth 2), k-chunks phase, phase+1
        half8 B0[4], B1[4];
        {
            int k0 = phase, k1 = (phase + 1) & 15;
#pragma unroll
            for (int mf = 0; mf < 4; ++mf) B0[mf] = *(const half8*)(zr + ((k0 * 4 + mf) * 64 + lane) * 8);
#pragma unroll
            for (int mf = 0; mf < 4; ++mf) B1[mf] = *(const half8*)(zr + ((k1 * 4 + mf) * 64 + lane) * 8);
        }

        // acc starts at x: MFMA C-in accumulates, epilogue add eliminated
        float4v acc[4][4];
#pragma unroll
        for (int f = 0; f < 4; ++f)
#pragma unroll
            for (int mf = 0; mf < 4; ++mf) acc[f][mf] = xr[f][mf];

#pragma unroll
        for (int ks = 0; ks < 16; ++ks) {
            half8* Ac = (ks & 1) ? A1 : A0;
            half8* Bc = (ks & 1) ? B1 : B0;
#pragma unroll
            for (int f = 0; f < 4; ++f)
#pragma unroll
                for (int mf = 0; mf < 4; ++mf)
                    acc[f][mf] = __builtin_amdgcn_mfma_f32_16x16x32_f16(Ac[f], Bc[mf], acc[f][mf], 0, 0, 0);
            // Refill just-consumed A buffer with sweep step ks+2 (mod 16):
            // at ks=14,15 this is k-chunk phase / phase+1 again = the NEXT
            // iteration's first steps -> prefetch survives the lgkm barrier.
            int ka = (phase + ks + 2) & 15;
#pragma unroll
            for (int f = 0; f < 4; ++f) Ac[f] = Wv[(ka * 32 + f) * 64];
            // Refill B with sweep step ks+2 from the SAME z buffer (cannot
            // cross the barrier: other buffer not yet written).
            if (ks < 14) {
#pragma unroll
                for (int mf = 0; mf < 4; ++mf)
                    Bc[mf] = *(const half8*)(zr + ((ka * 4 + mf) * 64 + lane) * 8);
            }
        }

        if (it < NITER - 2) {
            // z_{k+1} = tanh(acc) -> other buffer (readers on zsh[p], writers
            // on zsh[p^1]: one barrier per iteration is sufficient).
            _Float16* zw = &zsh[p ^ 1][0];
#pragma unroll
            for (int f = 0; f < 4; ++f) {
                int n = (nf0 + f) * 16 + quad * 4;
#pragma unroll
                for (int mf = 0; mf < 4; ++mf) {
                    int m = mf * 16 + l15;
                    half4v h;
#pragma unroll
                    for (int j = 0; j < 4; ++j) h[j] = (_Float16)fast_tanh(acc[f][mf][j]);
                    *(half4v*)(zw + zaddr(m, n)) = h;
                }
            }
            // Barrier WITHOUT vmcnt drain: LDS writes must be visible
            // (lgkmcnt(0)), but in-flight global A-prefetch loads stay live.
            asm volatile("s_waitcnt lgkmcnt(0)\n\ts_barrier" ::: "memory");
            p ^= 1;
        } else {
            // final iteration: store z50 straight from registers (fp32, nt)
#pragma unroll
            for (int f = 0; f < 4; ++f) {
                int n = (nf0 + f) * 16 + quad * 4;
#pragma unroll
                for (int mf = 0; mf < 4; ++mf) {
                    float4v v;
#pragma unroll
                    for (int j = 0; j < 4; ++j) v[j] = fast_tanh(acc[f][mf][j]);
                    float4v* op = (float4v*)(out + (size_t)(row_blk + mf * 16 + l15) * DDIM + n);
                    __builtin_nontemporal_store(v, op);
                }
            }
        }
    }
}

extern "C" void kernel_launch(void* const* d_in, const int* in_sizes, int n_in,
                              void* d_out, int out_size, void* d_ws, size_t ws_size,
                              hipStream_t stream) {
    const float* x = (const float*)d_in[0];   // [65536, 512] fp32
    const float* W = (const float*)d_in[1];   // [512, 512] fp32
    _Float16* Wpk = (_Float16*)d_ws;          // 512 KB packed f16 W
    float* out = (float*)d_out;

    wpack_kernel<<<128, 256, 0, stream>>>(W, Wpk);
    fixpoint_kernel<<<65536 / MTILE, 512, 0, stream>>>(x, Wpk, out);
}